// Round 5
// baseline (583.498 us; speedup 1.0000x reference)
//
#include <hip/hip_runtime.h>
#include <hip/hip_fp16.h>

// Persistent grid-stride version with register double-buffering: ~6K waves
// live for the whole kernel; each loop iteration issues the NEXT tile's 8
// loads (uint4, coalesced: lane i at base+i*16B) before computing/storing
// the CURRENT tile, so the vmem queue never drains at wave boundaries.
// Bits extracted from float 0.0/1.0 patterns via (u>>23)&1 (1.0f=0x3F800000)
// -- no v_cvt. Row gather via shfl_xor(1)/shfl_xor(2) quad nibble-OR (DPP);
// all 4 lanes of a quad redundantly do the fp16 add (VALU ~90% idle), each
// stores its own quarter -> coalesced normal (cached) stores.

__global__ __launch_bounds__(256) void spike_fp16_add_kernel(
    const uint4* __restrict__ A, const uint4* __restrict__ B,
    float4* __restrict__ O, int nf4, int waveStride)  // strides in float4 units
{
    const int lane = threadIdx.x & 63;
    const int waveId = (blockIdx.x * blockDim.x + threadIdx.x) >> 6;
    const int q = lane & 3;
    const int sh = 12 - 4 * q;          // MSB-first nibble position for this quarter
    const int nf4_full = nf4 & ~255;    // full 256-f4 tiles

    int base = waveId * 256;

    if (base < nf4_full) {
        uint4 a0[4], b0[4], a1[4], b1[4];
        int idx = base + lane;
        #pragma unroll
        for (int k = 0; k < 4; ++k) a0[k] = A[idx + k * 64];
        #pragma unroll
        for (int k = 0; k < 4; ++k) b0[k] = B[idx + k * 64];

        while (true) {
            const int nbase = base + waveStride;        // wave-uniform
            const bool hasNext = (nbase < nf4_full);    // scalar branch
            const int nidx = idx + waveStride;
            if (hasNext) {
                #pragma unroll
                for (int k = 0; k < 4; ++k) a1[k] = A[nidx + k * 64];
                #pragma unroll
                for (int k = 0; k < 4; ++k) b1[k] = B[nidx + k * 64];
            }

            #pragma unroll
            for (int k = 0; k < 4; ++k) {
                uint32_t ua = (((a0[k].x >> 20) & 8u) | ((a0[k].y >> 21) & 4u) |
                               ((a0[k].z >> 22) & 2u) | ((a0[k].w >> 23) & 1u)) << sh;
                uint32_t ub = (((b0[k].x >> 20) & 8u) | ((b0[k].y >> 21) & 4u) |
                               ((b0[k].z >> 22) & 2u) | ((b0[k].w >> 23) & 1u)) << sh;

                ua |= (uint32_t)__shfl_xor((int)ua, 1);
                ua |= (uint32_t)__shfl_xor((int)ua, 2);
                ub |= (uint32_t)__shfl_xor((int)ub, 1);
                ub |= (uint32_t)__shfl_xor((int)ub, 2);

                // fp16 add via exact fp32 add + RNE convert (bit-exact, Figueroa)
                float fa = __half2float(__ushort_as_half((unsigned short)ua));
                float fb = __half2float(__ushort_as_half((unsigned short)ub));
                uint32_t us = (uint32_t)__half_as_ushort(__float2half_rn(fa + fb));

                uint32_t ns = (us >> sh) & 0xFu;
                float4 o;
                o.x = (float)((ns >> 3) & 1u);
                o.y = (float)((ns >> 2) & 1u);
                o.z = (float)((ns >> 1) & 1u);
                o.w = (float)( ns       & 1u);
                O[idx + k * 64] = o;
            }

            if (!hasNext) break;
            #pragma unroll
            for (int k = 0; k < 4; ++k) { a0[k] = a1[k]; b0[k] = b1[k]; }
            base = nbase;
            idx = nidx;
        }
    }

    // Tail: nf4 not a multiple of 256 (not hit at N=4194304). Rows are 4 f4,
    // so quads are all-in or all-out -> shfl quad combine stays coherent.
    const int tail = nf4 - nf4_full;
    if (tail > 0) {
        const int gid = blockIdx.x * blockDim.x + threadIdx.x;
        if (gid < 256) {                 // whole waves of block 0
            const int f4 = nf4_full + gid;
            uint32_t ua = 0, ub = 0;
            if (f4 < nf4) {
                uint4 a = A[f4], b = B[f4];
                ua = (((a.x >> 20) & 8u) | ((a.y >> 21) & 4u) |
                      ((a.z >> 22) & 2u) | ((a.w >> 23) & 1u)) << sh;
                ub = (((b.x >> 20) & 8u) | ((b.y >> 21) & 4u) |
                      ((b.z >> 22) & 2u) | ((b.w >> 23) & 1u)) << sh;
            }
            ua |= (uint32_t)__shfl_xor((int)ua, 1);
            ua |= (uint32_t)__shfl_xor((int)ua, 2);
            ub |= (uint32_t)__shfl_xor((int)ub, 1);
            ub |= (uint32_t)__shfl_xor((int)ub, 2);
            float fa = __half2float(__ushort_as_half((unsigned short)ua));
            float fb = __half2float(__ushort_as_half((unsigned short)ub));
            uint32_t us = (uint32_t)__half_as_ushort(__float2half_rn(fa + fb));
            uint32_t ns = (us >> sh) & 0xFu;
            float4 o;
            o.x = (float)((ns >> 3) & 1u);
            o.y = (float)((ns >> 2) & 1u);
            o.z = (float)((ns >> 1) & 1u);
            o.w = (float)( ns       & 1u);
            if (f4 < nf4) O[f4] = o;
        }
    }
}

extern "C" void kernel_launch(void* const* d_in, const int* in_sizes, int n_in,
                              void* d_out, int out_size, void* d_ws, size_t ws_size,
                              hipStream_t stream) {
    const uint4* A = (const uint4*)d_in[0];
    const uint4* B = (const uint4*)d_in[1];
    float4* O = (float4*)d_out;

    int nf4 = in_sizes[0] / 4;          // total float4s per input
    int block = 256;
    // Persistent-ish grid: ~6 blocks/CU (VGPR-limited occupancy estimate).
    int grid = 1536;
    int totalWaves = grid * (block / 64);
    int waveStride = totalWaves * 256;  // f4 per full sweep

    spike_fp16_add_kernel<<<grid, block, 0, stream>>>(A, B, O, nf4, waveStride);
}